// Round 10
// baseline (291.299 us; speedup 1.0000x reference)
//
#include <hip/hip_runtime.h>
#include <stdint.h>

// Problem constants
#define B 8
#define N 2048
#define D 16
#define KNN 32
#define DM 256
#define CAP 96   // tie-fixup cap; degenerate all-tie batches still rank correctly
#define QPB 4    // queries (waves) per block
#define RPAD 20  // staged row stride in floats: 80 B, 16B-aligned -> b128 LDS ops,
                 // start banks (20*l)%32 cover all 32 banks per 8 lanes -> conflict-free

// ---------------------------------------------------------------------------
// K1: fused prep (proven since round 5, verbatim). Blocks 0..63: own-batch
// fp64 stats, then per-point masked x_crd row -> xcrd, sq, Tc/Tf.
// Block 64: W transpose + pe bias/loss.
// ---------------------------------------------------------------------------
__global__ __launch_bounds__(256) void knn_prep(
    const float* __restrict__ x, const float* __restrict__ features,
    const float* __restrict__ Wc, const float* __restrict__ Wf,
    const float* __restrict__ pec, const float* __restrict__ pef,
    float* __restrict__ xcrd, float* __restrict__ sq,
    float* __restrict__ Tc, float* __restrict__ Tf,
    float* __restrict__ WcT, float* __restrict__ WfT,
    float* __restrict__ cbias, float* __restrict__ pe_loss_out)
{
    if (blockIdx.x == 64) {
        int dm = threadIdx.x;
        float cb = 0.f, al = 0.f;
#pragma unroll
        for (int p = 0; p < D; ++p)
            cb += pec[p * DM + dm] + pef[p * DM + dm];
#pragma unroll
        for (int p = 0; p < D; ++p)
            al += fabsf(pec[p * DM + dm]) + fabsf(pef[p * DM + dm]);
        cbias[dm] = cb;
#pragma unroll
        for (int k = 0; k < KNN; ++k) {
            WcT[k * DM + dm] = Wc[dm * KNN + k];
            WfT[k * DM + dm] = Wf[dm * KNN + k];
        }
        __shared__ float redf[256];
        redf[dm] = al; __syncthreads();
        for (int st = 128; st > 0; st >>= 1) {
            if (dm < st) redf[dm] += redf[dm + st];
            __syncthreads();
        }
        if (dm == 0) pe_loss_out[0] = redf[0];
        return;
    }

    int tid = threadIdx.x;
    int b = blockIdx.x >> 3;

    // ---- own-batch stats: 8 rows per thread, fp64 accumulate ----
    double ls[D], lq[D];
#pragma unroll
    for (int d = 0; d < D; ++d) { ls[d] = 0.0; lq[d] = 0.0; }
    for (int r = 0; r < 8; ++r) {
        const float* row = x + ((size_t)b * N + r * 256 + tid) * D;
#pragma unroll
        for (int d = 0; d < D; d += 4) {
            float4 v = *(const float4*)(row + d);
            double x0 = v.x, x1 = v.y, x2 = v.z, x3 = v.w;
            ls[d]   += x0; lq[d]   += x0 * x0;
            ls[d+1] += x1; lq[d+1] += x1 * x1;
            ls[d+2] += x2; lq[d+2] += x2 * x2;
            ls[d+3] += x3; lq[d+3] += x3 * x3;
        }
    }
#pragma unroll
    for (int d = 0; d < D; ++d) {
        double s = ls[d], q = lq[d];
#pragma unroll
        for (int st = 32; st >= 1; st >>= 1) {
            s += __shfl_xor(s, st, 64);
            q += __shfl_xor(q, st, 64);
        }
        ls[d] = s; lq[d] = q;
    }
    __shared__ double sred[4][2 * D];
    __shared__ float smean[32], sscale[32];
    int wave = tid >> 6, lane = tid & 63;
    if (lane == 0) {
#pragma unroll
        for (int d = 0; d < D; ++d) {
            sred[wave][d]     = ls[d];
            sred[wave][D + d] = lq[d];
        }
    }
    __syncthreads();
    if (tid < D) {
        int d = tid;
        double S = sred[0][d] + sred[1][d] + sred[2][d] + sred[3][d];
        double Q = sred[0][D+d] + sred[1][D+d] + sred[2][D+d] + sred[3][D+d];
        double mean = S / (double)N;
        double var  = (Q - S * S / (double)N) / (double)(N - 1);
        if (var < 0.0) var = 0.0;
        float stdv = (float)sqrt(var);
        float scl  = 1.0f / (stdv + 1e-5f);
        float scl0 = 1.0f / (0.0f + 1e-5f);
        bool mask = features[b * D + d] > 0.1f;
        smean [d]      = mask ? 0.0f : (float)mean;
        sscale[d]      = mask ? scl0 : scl;
        smean [16 + d] = mask ? (float)mean : 0.0f;
        sscale[16 + d] = mask ? scl : scl0;
    }
    __syncthreads();

    // ---- per-point processing (identical arithmetic to rounds 1-9) ----
    int t = blockIdx.x * 256 + tid;
    float tc = 0.f, tf = 0.f, s = 0.f;
    float row[D];
#pragma unroll
    for (int d = 0; d < D; ++d) {
        float xv = x[(size_t)t * D + d];
        bool mask = features[b * D + d] > 0.1f;
        float xc = mask ? 0.f : xv;
        float xf = mask ? xv : 0.f;
        row[d] = xc;
        s += xc * xc;                            // sequential, mirrors ref sq
        float vc = (xc - smean[d])      * sscale[d];
        vc = fminf(10.f, fmaxf(-10.f, vc));
        float vf = (xf - smean[16 + d]) * sscale[16 + d];
        vf = fminf(10.f, fmaxf(-10.f, vf));
        tc += vc; tf += vf;
    }
#pragma unroll
    for (int d = 0; d < D; d += 4)
        *(float4*)(xcrd + (size_t)t * D + d) =
            make_float4(row[d], row[d+1], row[d+2], row[d+3]);
    sq[t] = s; Tc[t] = tc; Tf[t] = tf;
}

// ---------------------------------------------------------------------------
// K2: 4 queries per 256-thread block (one per wave).  Fill: 8 cooperative
// LDS-staged tiles of 256 candidate rows (RPAD=20: 16B-aligned rows ->
// ds_write_b128/ds_read_b128, conflict-free).  Each wave computes its 4
// j-values per tile from LDS with the SAME ascending-channel fma chain as
// round 8 -> bit-identical distances.  Selection (proven round 8): per-lane
// bitonic sort of f32 values, 6 xor-butterfly min-32 merge rounds -> tau =
// exact 32nd-smallest, then tie-fixup ballot-compaction + unique-key
// ranking (per-wave LDS regions).
// __launch_bounds__(256,3): ~170-VGPR cap — rounds 3/9 proved a 128 cap
// scratch-spills this live set (~140 regs); 170 clears it.
// ---------------------------------------------------------------------------
__global__ __launch_bounds__(256, 3) void knn_main(
    const float* __restrict__ xcrd, const float* __restrict__ sq,
    const float* __restrict__ Tc, const float* __restrict__ Tf,
    const float* __restrict__ WcT, const float* __restrict__ WfT,
    const float* __restrict__ cbias, float* __restrict__ out)
{
    __shared__ float tile[256 * RPAD];                    // 20480 B
    __shared__ unsigned long long collect[QPB][CAP];      // 3072 B
    __shared__ int sortedm[QPB][KNN];                     // 512 B

    const int tid  = threadIdx.x;
    const int wave = tid >> 6;
    const int lane = tid & 63;
    const int qid  = blockIdx.x * QPB + wave;    // 0..16383
    const int b = qid >> 11;
    const int n = qid & (N - 1);

    const float* xb  = xcrd + (size_t)b * N * D;
    const float* sqb = sq + b * N;

    // query row
    float qx[D];
#pragma unroll
    for (int d = 0; d < D; d += 4) {
        float4 v = *(const float4*)(xb + (size_t)n * D + d);
        qx[d] = v.x; qx[d+1] = v.y; qx[d+2] = v.z; qx[d+3] = v.w;
    }
    const float sqn = sqb[n];

    // ---- fill via LDS-staged tiles; distance bits identical to round 8 ----
    float orig[KNN], srt[KNN];
#pragma unroll 1
    for (int t = 0; t < 8; ++t) {
        __syncthreads();
        {   // stage row (t*256 + tid) into tile[tid*RPAD .. +15] (b128 ops)
            const float* xr = xb + (size_t)(t * 256 + tid) * D;
            float4 a0 = *(const float4*)(xr);
            float4 a1 = *(const float4*)(xr + 4);
            float4 a2 = *(const float4*)(xr + 8);
            float4 a3 = *(const float4*)(xr + 12);
            float* dst = tile + tid * RPAD;
            *(float4*)(dst)      = a0;
            *(float4*)(dst + 4)  = a1;
            *(float4*)(dst + 8)  = a2;
            *(float4*)(dst + 12) = a3;
        }
        __syncthreads();
#pragma unroll
        for (int jj = 0; jj < 4; ++jj) {
            const int j = t * 4 + jj;
            const int m = j * 64 + lane;         // == t*256 + jj*64 + lane
            const float* row = tile + (jj * 64 + lane) * RPAD;
            float4 v0 = *(const float4*)(row);
            float4 v1 = *(const float4*)(row + 4);
            float4 v2 = *(const float4*)(row + 8);
            float4 v3 = *(const float4*)(row + 12);
            float dot = 0.f;
            dot += qx[0]  * v0.x; dot += qx[1]  * v0.y;
            dot += qx[2]  * v0.z; dot += qx[3]  * v0.w;
            dot += qx[4]  * v1.x; dot += qx[5]  * v1.y;
            dot += qx[6]  * v1.z; dot += qx[7]  * v1.w;
            dot += qx[8]  * v2.x; dot += qx[9]  * v2.y;
            dot += qx[10] * v2.z; dot += qx[11] * v2.w;
            dot += qx[12] * v3.x; dot += qx[13] * v3.y;
            dot += qx[14] * v3.z; dot += qx[15] * v3.w;
            float d2 = sqn + sqb[m] - 2.0f * dot;
            float dist = fabsf(sqrtf(fmaxf(d2, 0.f)));   // fabs: -0 -> +0
            orig[j] = dist; srt[j] = dist;
        }
    }

    // ---- per-lane bitonic sort (ascending) of the value copy ----
#pragma unroll
    for (int kk = 2; kk <= KNN; kk <<= 1) {
#pragma unroll
        for (int jj = kk >> 1; jj > 0; jj >>= 1) {
#pragma unroll
            for (int i = 0; i < KNN; ++i) {
                int l = i ^ jj;
                if (l > i) {
                    float a = srt[i], c2 = srt[l];
                    if ((i & kk) == 0) { srt[i] = fminf(a, c2); srt[l] = fmaxf(a, c2); }
                    else               { srt[i] = fmaxf(a, c2); srt[l] = fminf(a, c2); }
                }
            }
        }
    }

    // ---- 6 butterfly min-32 merge rounds (values only, duplicates ok) ----
#pragma unroll 1
    for (int s = 1; s <= 32; s <<= 1) {
#pragma unroll
        for (int i = 0; i < KNN / 2; ++i) {
            int r = KNN - 1 - i;
            float o_i = __shfl_xor(srt[r], s, 64);   // partner[31-i]
            float o_r = __shfl_xor(srt[i], s, 64);   // partner[31-r]
            srt[i] = fminf(srt[i], o_i);
            srt[r] = fminf(srt[r], o_r);
        }
#pragma unroll
        for (int jj = 16; jj >= 1; jj >>= 1) {
#pragma unroll
            for (int i = 0; i < KNN; ++i) {
                if ((i & jj) == 0) {
                    int l = i + jj;
                    float a = srt[i], c2 = srt[l];
                    srt[i] = fminf(a, c2);
                    srt[l] = fmaxf(a, c2);
                }
            }
        }
    }
    const float tau = srt[31];                   // exact 32nd smallest value

    // ---- tie-fixup: compact all dist <= tau in ascending global-index order ----
    const unsigned long long lmask = (1ULL << lane) - 1ULL;
    int base = 0;
#pragma unroll
    for (int j = 0; j < KNN; ++j) {
        bool f = (orig[j] <= tau);
        unsigned long long mk = __ballot(f);
        if (f) {
            int pos = base + (int)__popcll(mk & lmask);
            if (pos < CAP)
                collect[wave][pos] =
                    (((unsigned long long)__float_as_uint(orig[j])) << 11)
                    | (unsigned)(j * 64 + lane);
        }
        base += (int)__popcll(mk);
    }
    int T = base < CAP ? base : CAP;             // wave-uniform, >= 32
    __syncthreads();

    // ---- rank the T collected items (keys globally unique, wave-local) ----
#pragma unroll 1
    for (int slot = 0; slot < 2; ++slot) {
        int i = lane + slot * 64;
        if (i < T) {
            unsigned long long mk = collect[wave][i];
            int rank = 0;
#pragma unroll 1
            for (int t2 = 0; t2 < T; ++t2)
                rank += (collect[wave][t2] < mk) ? 1 : 0;
            if (rank < KNN)
                sortedm[wave][rank] = (int)(mk & 2047u);
        }
    }
    __syncthreads();

    // ---- matvec: ranked top-32 ----
    float acc[4] = {0.f, 0.f, 0.f, 0.f};
    const float* Tcb = Tc + b * N;
    const float* Tfb = Tf + b * N;
    const float Tcn = Tcb[n], Tfn = Tfb[n];

#pragma unroll
    for (int k = 0; k < KNN; ++k) {
        int wm = sortedm[wave][k];
        float ak = Tcb[wm] - Tcn;
        float bk = Tfb[wm] - Tfn;
        const float* wc = WcT + k * DM + lane;
        const float* wf = WfT + k * DM + lane;
#pragma unroll
        for (int q = 0; q < 4; ++q)
            acc[q] += wc[q * 64] * ak + wf[q * 64] * bk;
    }

    size_t obase = (size_t)qid * DM + lane;
#pragma unroll
    for (int q = 0; q < 4; ++q)
        out[obase + q * 64] = acc[q] + cbias[lane + q * 64];
}

// ---------------------------------------------------------------------------
extern "C" void kernel_launch(void* const* d_in, const int* in_sizes, int n_in,
                              void* d_out, int out_size, void* d_ws, size_t ws_size,
                              hipStream_t stream)
{
    const float* x        = (const float*)d_in[0];   // (B,N,D)
    const float* features = (const float*)d_in[1];   // (B,D)
    const float* W_crd    = (const float*)d_in[2];   // (DM,K)
    const float* W_ftr    = (const float*)d_in[3];   // (DM,K)
    const float* pe_crd   = (const float*)d_in[4];   // (1,1,D,DM)
    const float* pe_ftr   = (const float*)d_in[5];   // (1,1,D,DM)
    // d_in[6] = k (constant 32), ignored

    float* out = (float*)d_out;                      // B*N*DM floats + 1 (pe_loss)

    float* xcrd  = (float*)d_ws;                     // 262144
    float* sqv   = xcrd + (size_t)B * N * D;         // 16384
    float* Tc    = sqv  + B * N;                     // 16384
    float* Tf    = Tc   + B * N;                     // 16384
    float* cbias = Tf   + B * N;                     // 256
    float* WcT   = cbias + DM;                       // 8192
    float* WfT   = WcT + KNN * DM;                   // 8192

    knn_prep<<<65, 256, 0, stream>>>(x, features, W_crd, W_ftr, pe_crd, pe_ftr,
                                     xcrd, sqv, Tc, Tf, WcT, WfT, cbias,
                                     out + (size_t)out_size - 1);
    knn_main<<<B * N / QPB, 256, 0, stream>>>(xcrd, sqv, Tc, Tf,
                                              WcT, WfT, cbias, out);
}

// Round 11
// 267.524 us; speedup vs baseline: 1.0889x; 1.0889x over previous
//
#include <hip/hip_runtime.h>
#include <stdint.h>

// Problem constants
#define B 8
#define N 2048
#define D 16
#define KNN 32
#define DM 256
#define CAP 96   // tie-fixup cap; degenerate all-tie batches still rank correctly
#define QPB 4    // queries (waves) per block
#define RPAD 17  // staged row stride in floats; odd stride -> scalar b32 LDS ops,
                 // measured ZERO bank conflicts (round 9)

// ---------------------------------------------------------------------------
// K1: fused prep (proven since round 5, verbatim). Blocks 0..63: own-batch
// fp64 stats, then per-point masked x_crd row -> xcrd, sq, Tc/Tf.
// Block 64: W transpose + pe bias/loss.
// ---------------------------------------------------------------------------
__global__ __launch_bounds__(256) void knn_prep(
    const float* __restrict__ x, const float* __restrict__ features,
    const float* __restrict__ Wc, const float* __restrict__ Wf,
    const float* __restrict__ pec, const float* __restrict__ pef,
    float* __restrict__ xcrd, float* __restrict__ sq,
    float* __restrict__ Tc, float* __restrict__ Tf,
    float* __restrict__ WcT, float* __restrict__ WfT,
    float* __restrict__ cbias, float* __restrict__ pe_loss_out)
{
    if (blockIdx.x == 64) {
        int dm = threadIdx.x;
        float cb = 0.f, al = 0.f;
#pragma unroll
        for (int p = 0; p < D; ++p)
            cb += pec[p * DM + dm] + pef[p * DM + dm];
#pragma unroll
        for (int p = 0; p < D; ++p)
            al += fabsf(pec[p * DM + dm]) + fabsf(pef[p * DM + dm]);
        cbias[dm] = cb;
#pragma unroll
        for (int k = 0; k < KNN; ++k) {
            WcT[k * DM + dm] = Wc[dm * KNN + k];
            WfT[k * DM + dm] = Wf[dm * KNN + k];
        }
        __shared__ float redf[256];
        redf[dm] = al; __syncthreads();
        for (int st = 128; st > 0; st >>= 1) {
            if (dm < st) redf[dm] += redf[dm + st];
            __syncthreads();
        }
        if (dm == 0) pe_loss_out[0] = redf[0];
        return;
    }

    int tid = threadIdx.x;
    int b = blockIdx.x >> 3;

    // ---- own-batch stats: 8 rows per thread, fp64 accumulate ----
    double ls[D], lq[D];
#pragma unroll
    for (int d = 0; d < D; ++d) { ls[d] = 0.0; lq[d] = 0.0; }
    for (int r = 0; r < 8; ++r) {
        const float* row = x + ((size_t)b * N + r * 256 + tid) * D;
#pragma unroll
        for (int d = 0; d < D; d += 4) {
            float4 v = *(const float4*)(row + d);
            double x0 = v.x, x1 = v.y, x2 = v.z, x3 = v.w;
            ls[d]   += x0; lq[d]   += x0 * x0;
            ls[d+1] += x1; lq[d+1] += x1 * x1;
            ls[d+2] += x2; lq[d+2] += x2 * x2;
            ls[d+3] += x3; lq[d+3] += x3 * x3;
        }
    }
#pragma unroll
    for (int d = 0; d < D; ++d) {
        double s = ls[d], q = lq[d];
#pragma unroll
        for (int st = 32; st >= 1; st >>= 1) {
            s += __shfl_xor(s, st, 64);
            q += __shfl_xor(q, st, 64);
        }
        ls[d] = s; lq[d] = q;
    }
    __shared__ double sred[4][2 * D];
    __shared__ float smean[32], sscale[32];
    int wave = tid >> 6, lane = tid & 63;
    if (lane == 0) {
#pragma unroll
        for (int d = 0; d < D; ++d) {
            sred[wave][d]     = ls[d];
            sred[wave][D + d] = lq[d];
        }
    }
    __syncthreads();
    if (tid < D) {
        int d = tid;
        double S = sred[0][d] + sred[1][d] + sred[2][d] + sred[3][d];
        double Q = sred[0][D+d] + sred[1][D+d] + sred[2][D+d] + sred[3][D+d];
        double mean = S / (double)N;
        double var  = (Q - S * S / (double)N) / (double)(N - 1);
        if (var < 0.0) var = 0.0;
        float stdv = (float)sqrt(var);
        float scl  = 1.0f / (stdv + 1e-5f);
        float scl0 = 1.0f / (0.0f + 1e-5f);
        bool mask = features[b * D + d] > 0.1f;
        smean [d]      = mask ? 0.0f : (float)mean;
        sscale[d]      = mask ? scl0 : scl;
        smean [16 + d] = mask ? (float)mean : 0.0f;
        sscale[16 + d] = mask ? scl : scl0;
    }
    __syncthreads();

    // ---- per-point processing (identical arithmetic to rounds 1-10) ----
    int t = blockIdx.x * 256 + tid;
    float tc = 0.f, tf = 0.f, s = 0.f;
    float row[D];
#pragma unroll
    for (int d = 0; d < D; ++d) {
        float xv = x[(size_t)t * D + d];
        bool mask = features[b * D + d] > 0.1f;
        float xc = mask ? 0.f : xv;
        float xf = mask ? xv : 0.f;
        row[d] = xc;
        s += xc * xc;                            // sequential, mirrors ref sq
        float vc = (xc - smean[d])      * sscale[d];
        vc = fminf(10.f, fmaxf(-10.f, vc));
        float vf = (xf - smean[16 + d]) * sscale[16 + d];
        vf = fminf(10.f, fmaxf(-10.f, vf));
        tc += vc; tf += vf;
    }
#pragma unroll
    for (int d = 0; d < D; d += 4)
        *(float4*)(xcrd + (size_t)t * D + d) =
            make_float4(row[d], row[d+1], row[d+2], row[d+3]);
    sq[t] = s; Tc[t] = tc; Tf[t] = tf;
}

// ---------------------------------------------------------------------------
// K2: 4 queries per 256-thread block (one per wave).  Fill: 8 cooperative
// LDS-staged tiles of 256 candidate rows, RPAD=17 (odd stride, scalar b32
// LDS ops — round 9 measured ZERO bank conflicts).  Each wave computes its
// 4 j-values per tile from LDS with the same ascending-channel fma chain
// as round 8.  Selection (proven round 8): per-lane bitonic sort of f32
// values, 6 xor-butterfly min-32 merge rounds -> tau = exact 32nd-smallest,
// then tie-fixup ballot-compaction + unique-key ranking (per-wave LDS).
// __launch_bounds__(256,3): ~170-VGPR cap — 128-cap spills this live set
// (rounds 3/9); round 10 verified (256,3) runs with ZERO scratch traffic.
// ---------------------------------------------------------------------------
__global__ __launch_bounds__(256, 3) void knn_main(
    const float* __restrict__ xcrd, const float* __restrict__ sq,
    const float* __restrict__ Tc, const float* __restrict__ Tf,
    const float* __restrict__ WcT, const float* __restrict__ WfT,
    const float* __restrict__ cbias, float* __restrict__ out)
{
    __shared__ float tile[256 * RPAD];                    // 17408 B
    __shared__ unsigned long long collect[QPB][CAP];      // 3072 B
    __shared__ int sortedm[QPB][KNN];                     // 512 B

    const int tid  = threadIdx.x;
    const int wave = tid >> 6;
    const int lane = tid & 63;
    const int qid  = blockIdx.x * QPB + wave;    // 0..16383
    const int b = qid >> 11;
    const int n = qid & (N - 1);

    const float* xb  = xcrd + (size_t)b * N * D;
    const float* sqb = sq + b * N;

    // query row
    float qx[D];
#pragma unroll
    for (int d = 0; d < D; d += 4) {
        float4 v = *(const float4*)(xb + (size_t)n * D + d);
        qx[d] = v.x; qx[d+1] = v.y; qx[d+2] = v.z; qx[d+3] = v.w;
    }
    const float sqn = sqb[n];

    // ---- fill via LDS-staged tiles (scalar b32 LDS ops, conflict-free) ----
    float orig[KNN], srt[KNN];
#pragma unroll 1
    for (int t = 0; t < 8; ++t) {
        __syncthreads();
        {   // stage row (t*256 + tid) into tile[tid*RPAD .. +15]
            const float* xr = xb + (size_t)(t * 256 + tid) * D;
            float4 a0 = *(const float4*)(xr);
            float4 a1 = *(const float4*)(xr + 4);
            float4 a2 = *(const float4*)(xr + 8);
            float4 a3 = *(const float4*)(xr + 12);
            float* dst = tile + tid * RPAD;
            dst[0]  = a0.x; dst[1]  = a0.y; dst[2]  = a0.z; dst[3]  = a0.w;
            dst[4]  = a1.x; dst[5]  = a1.y; dst[6]  = a1.z; dst[7]  = a1.w;
            dst[8]  = a2.x; dst[9]  = a2.y; dst[10] = a2.z; dst[11] = a2.w;
            dst[12] = a3.x; dst[13] = a3.y; dst[14] = a3.z; dst[15] = a3.w;
        }
        __syncthreads();
#pragma unroll
        for (int jj = 0; jj < 4; ++jj) {
            const int j = t * 4 + jj;
            const int m = j * 64 + lane;         // == t*256 + jj*64 + lane
            const float* row = tile + (jj * 64 + lane) * RPAD;
            float dot = 0.f;
            dot += qx[0]  * row[0];  dot += qx[1]  * row[1];
            dot += qx[2]  * row[2];  dot += qx[3]  * row[3];
            dot += qx[4]  * row[4];  dot += qx[5]  * row[5];
            dot += qx[6]  * row[6];  dot += qx[7]  * row[7];
            dot += qx[8]  * row[8];  dot += qx[9]  * row[9];
            dot += qx[10] * row[10]; dot += qx[11] * row[11];
            dot += qx[12] * row[12]; dot += qx[13] * row[13];
            dot += qx[14] * row[14]; dot += qx[15] * row[15];
            float d2 = sqn + sqb[m] - 2.0f * dot;
            float dist = fabsf(sqrtf(fmaxf(d2, 0.f)));   // fabs: -0 -> +0
            orig[j] = dist; srt[j] = dist;
        }
    }

    // ---- per-lane bitonic sort (ascending) of the value copy ----
#pragma unroll
    for (int kk = 2; kk <= KNN; kk <<= 1) {
#pragma unroll
        for (int jj = kk >> 1; jj > 0; jj >>= 1) {
#pragma unroll
            for (int i = 0; i < KNN; ++i) {
                int l = i ^ jj;
                if (l > i) {
                    float a = srt[i], c2 = srt[l];
                    if ((i & kk) == 0) { srt[i] = fminf(a, c2); srt[l] = fmaxf(a, c2); }
                    else               { srt[i] = fmaxf(a, c2); srt[l] = fminf(a, c2); }
                }
            }
        }
    }

    // ---- 6 butterfly min-32 merge rounds (values only, duplicates ok) ----
#pragma unroll 1
    for (int s = 1; s <= 32; s <<= 1) {
#pragma unroll
        for (int i = 0; i < KNN / 2; ++i) {
            int r = KNN - 1 - i;
            float o_i = __shfl_xor(srt[r], s, 64);   // partner[31-i]
            float o_r = __shfl_xor(srt[i], s, 64);   // partner[31-r]
            srt[i] = fminf(srt[i], o_i);
            srt[r] = fminf(srt[r], o_r);
        }
#pragma unroll
        for (int jj = 16; jj >= 1; jj >>= 1) {
#pragma unroll
            for (int i = 0; i < KNN; ++i) {
                if ((i & jj) == 0) {
                    int l = i + jj;
                    float a = srt[i], c2 = srt[l];
                    srt[i] = fminf(a, c2);
                    srt[l] = fmaxf(a, c2);
                }
            }
        }
    }
    const float tau = srt[31];                   // exact 32nd smallest value

    // ---- tie-fixup: compact all dist <= tau in ascending global-index order ----
    const unsigned long long lmask = (1ULL << lane) - 1ULL;
    int base = 0;
#pragma unroll
    for (int j = 0; j < KNN; ++j) {
        bool f = (orig[j] <= tau);
        unsigned long long mk = __ballot(f);
        if (f) {
            int pos = base + (int)__popcll(mk & lmask);
            if (pos < CAP)
                collect[wave][pos] =
                    (((unsigned long long)__float_as_uint(orig[j])) << 11)
                    | (unsigned)(j * 64 + lane);
        }
        base += (int)__popcll(mk);
    }
    int T = base < CAP ? base : CAP;             // wave-uniform, >= 32
    __syncthreads();

    // ---- rank the T collected items (keys globally unique, wave-local) ----
#pragma unroll 1
    for (int slot = 0; slot < 2; ++slot) {
        int i = lane + slot * 64;
        if (i < T) {
            unsigned long long mk = collect[wave][i];
            int rank = 0;
#pragma unroll 1
            for (int t2 = 0; t2 < T; ++t2)
                rank += (collect[wave][t2] < mk) ? 1 : 0;
            if (rank < KNN)
                sortedm[wave][rank] = (int)(mk & 2047u);
        }
    }
    __syncthreads();

    // ---- matvec: ranked top-32 ----
    float acc[4] = {0.f, 0.f, 0.f, 0.f};
    const float* Tcb = Tc + b * N;
    const float* Tfb = Tf + b * N;
    const float Tcn = Tcb[n], Tfn = Tfb[n];

#pragma unroll
    for (int k = 0; k < KNN; ++k) {
        int wm = sortedm[wave][k];
        float ak = Tcb[wm] - Tcn;
        float bk = Tfb[wm] - Tfn;
        const float* wc = WcT + k * DM + lane;
        const float* wf = WfT + k * DM + lane;
#pragma unroll
        for (int q = 0; q < 4; ++q)
            acc[q] += wc[q * 64] * ak + wf[q * 64] * bk;
    }

    size_t obase = (size_t)qid * DM + lane;
#pragma unroll
    for (int q = 0; q < 4; ++q)
        out[obase + q * 64] = acc[q] + cbias[lane + q * 64];
}

// ---------------------------------------------------------------------------
extern "C" void kernel_launch(void* const* d_in, const int* in_sizes, int n_in,
                              void* d_out, int out_size, void* d_ws, size_t ws_size,
                              hipStream_t stream)
{
    const float* x        = (const float*)d_in[0];   // (B,N,D)
    const float* features = (const float*)d_in[1];   // (B,D)
    const float* W_crd    = (const float*)d_in[2];   // (DM,K)
    const float* W_ftr    = (const float*)d_in[3];   // (DM,K)
    const float* pe_crd   = (const float*)d_in[4];   // (1,1,D,DM)
    const float* pe_ftr   = (const float*)d_in[5];   // (1,1,D,DM)
    // d_in[6] = k (constant 32), ignored

    float* out = (float*)d_out;                      // B*N*DM floats + 1 (pe_loss)

    float* xcrd  = (float*)d_ws;                     // 262144
    float* sqv   = xcrd + (size_t)B * N * D;         // 16384
    float* Tc    = sqv  + B * N;                     // 16384
    float* Tf    = Tc   + B * N;                     // 16384
    float* cbias = Tf   + B * N;                     // 256
    float* WcT   = cbias + DM;                       // 8192
    float* WfT   = WcT + KNN * DM;                   // 8192

    knn_prep<<<65, 256, 0, stream>>>(x, features, W_crd, W_ftr, pe_crd, pe_ftr,
                                     xcrd, sqv, Tc, Tf, WcT, WfT, cbias,
                                     out + (size_t)out_size - 1);
    knn_main<<<B * N / QPB, 256, 0, stream>>>(xcrd, sqv, Tc, Tf,
                                              WcT, WfT, cbias, out);
}

// Round 12
// 248.633 us; speedup vs baseline: 1.1716x; 1.0760x over previous
//
#include <hip/hip_runtime.h>
#include <stdint.h>

// Problem constants
#define B 8
#define N 2048
#define D 16
#define KNN 32
#define DM 256
#define CAP 96   // tie-fixup cap; degenerate all-tie batches still rank correctly

// ---------------------------------------------------------------------------
// K1: fused prep (proven since round 5, verbatim). Blocks 0..63: own-batch
// fp64 stats, then per-point masked x_crd row -> xcrd, sq, Tc/Tf.
// Block 64: W transpose + pe bias/loss.
// ---------------------------------------------------------------------------
__global__ __launch_bounds__(256) void knn_prep(
    const float* __restrict__ x, const float* __restrict__ features,
    const float* __restrict__ Wc, const float* __restrict__ Wf,
    const float* __restrict__ pec, const float* __restrict__ pef,
    float* __restrict__ xcrd, float* __restrict__ sq,
    float* __restrict__ Tc, float* __restrict__ Tf,
    float* __restrict__ WcT, float* __restrict__ WfT,
    float* __restrict__ cbias, float* __restrict__ pe_loss_out)
{
    if (blockIdx.x == 64) {
        int dm = threadIdx.x;
        float cb = 0.f, al = 0.f;
#pragma unroll
        for (int p = 0; p < D; ++p)
            cb += pec[p * DM + dm] + pef[p * DM + dm];
#pragma unroll
        for (int p = 0; p < D; ++p)
            al += fabsf(pec[p * DM + dm]) + fabsf(pef[p * DM + dm]);
        cbias[dm] = cb;
#pragma unroll
        for (int k = 0; k < KNN; ++k) {
            WcT[k * DM + dm] = Wc[dm * KNN + k];
            WfT[k * DM + dm] = Wf[dm * KNN + k];
        }
        __shared__ float redf[256];
        redf[dm] = al; __syncthreads();
        for (int st = 128; st > 0; st >>= 1) {
            if (dm < st) redf[dm] += redf[dm + st];
            __syncthreads();
        }
        if (dm == 0) pe_loss_out[0] = redf[0];
        return;
    }

    int tid = threadIdx.x;
    int b = blockIdx.x >> 3;

    // ---- own-batch stats: 8 rows per thread, fp64 accumulate ----
    double ls[D], lq[D];
#pragma unroll
    for (int d = 0; d < D; ++d) { ls[d] = 0.0; lq[d] = 0.0; }
    for (int r = 0; r < 8; ++r) {
        const float* row = x + ((size_t)b * N + r * 256 + tid) * D;
#pragma unroll
        for (int d = 0; d < D; d += 4) {
            float4 v = *(const float4*)(row + d);
            double x0 = v.x, x1 = v.y, x2 = v.z, x3 = v.w;
            ls[d]   += x0; lq[d]   += x0 * x0;
            ls[d+1] += x1; lq[d+1] += x1 * x1;
            ls[d+2] += x2; lq[d+2] += x2 * x2;
            ls[d+3] += x3; lq[d+3] += x3 * x3;
        }
    }
#pragma unroll
    for (int d = 0; d < D; ++d) {
        double s = ls[d], q = lq[d];
#pragma unroll
        for (int st = 32; st >= 1; st >>= 1) {
            s += __shfl_xor(s, st, 64);
            q += __shfl_xor(q, st, 64);
        }
        ls[d] = s; lq[d] = q;
    }
    __shared__ double sred[4][2 * D];
    __shared__ float smean[32], sscale[32];
    int wave = tid >> 6, lane = tid & 63;
    if (lane == 0) {
#pragma unroll
        for (int d = 0; d < D; ++d) {
            sred[wave][d]     = ls[d];
            sred[wave][D + d] = lq[d];
        }
    }
    __syncthreads();
    if (tid < D) {
        int d = tid;
        double S = sred[0][d] + sred[1][d] + sred[2][d] + sred[3][d];
        double Q = sred[0][D+d] + sred[1][D+d] + sred[2][D+d] + sred[3][D+d];
        double mean = S / (double)N;
        double var  = (Q - S * S / (double)N) / (double)(N - 1);
        if (var < 0.0) var = 0.0;
        float stdv = (float)sqrt(var);
        float scl  = 1.0f / (stdv + 1e-5f);
        float scl0 = 1.0f / (0.0f + 1e-5f);
        bool mask = features[b * D + d] > 0.1f;
        smean [d]      = mask ? 0.0f : (float)mean;
        sscale[d]      = mask ? scl0 : scl;
        smean [16 + d] = mask ? (float)mean : 0.0f;
        sscale[16 + d] = mask ? scl : scl0;
    }
    __syncthreads();

    // ---- per-point processing (identical arithmetic to rounds 1-11) ----
    int t = blockIdx.x * 256 + tid;
    float tc = 0.f, tf = 0.f, s = 0.f;
    float row[D];
#pragma unroll
    for (int d = 0; d < D; ++d) {
        float xv = x[(size_t)t * D + d];
        bool mask = features[b * D + d] > 0.1f;
        float xc = mask ? 0.f : xv;
        float xf = mask ? xv : 0.f;
        row[d] = xc;
        s += xc * xc;                            // sequential, mirrors ref sq
        float vc = (xc - smean[d])      * sscale[d];
        vc = fminf(10.f, fmaxf(-10.f, vc));
        float vf = (xf - smean[16 + d]) * sscale[16 + d];
        vf = fminf(10.f, fmaxf(-10.f, vf));
        tc += vc; tf += vf;
    }
#pragma unroll
    for (int d = 0; d < D; d += 4)
        *(float4*)(xcrd + (size_t)t * D + d) =
            make_float4(row[d], row[d+1], row[d+2], row[d+3]);
    sq[t] = s; Tc[t] = tc; Tf[t] = tf;
}

// ---------------------------------------------------------------------------
// K2: one wave (one 64-thread block) per query — round-8 structure with the
// register footprint shrunk for occupancy:
//  * orig[] distance array lives in per-wave LDS (distL[j*64+lane]: own-lane
//    writes/reads only, lane-contiguous -> free 2-way bank aliasing), freeing
//    ~32 VGPRs of long-lived state.
//  * __launch_bounds__(64,4): 128-reg cap -> 4 waves/SIMD (16 waves/CU).
//    Live set is now ~90 regs (srt[32]+qx[16]+temps), safely under the cap
//    that spilled at ~140 live regs in rounds 3/9.
// Fill (direct L2 reads) + f32 value butterfly + tie-fixup are byte-identical
// to round 8 (proven absmax 0.03125).
// ---------------------------------------------------------------------------
__global__ __launch_bounds__(64, 4) void knn_main(
    const float* __restrict__ xcrd, const float* __restrict__ sq,
    const float* __restrict__ Tc, const float* __restrict__ Tf,
    const float* __restrict__ WcT, const float* __restrict__ WfT,
    const float* __restrict__ cbias, float* __restrict__ out)
{
    __shared__ float distL[KNN * 64];            // 8192 B: per-lane dist list
    __shared__ unsigned long long collect[CAP];  // 768 B
    __shared__ int sortedm[KNN];                 // 128 B

    const int lane = threadIdx.x;
    const int qid  = blockIdx.x;                 // 0..16383
    const int b = qid >> 11;
    const int n = qid & (N - 1);

    const float* xb  = xcrd + (size_t)b * N * D;
    const float* sqb = sq + b * N;

    // query row
    float qx[D];
#pragma unroll
    for (int d = 0; d < D; d += 4) {
        float4 v = *(const float4*)(xb + (size_t)n * D + d);
        qx[d] = v.x; qx[d+1] = v.y; qx[d+2] = v.z; qx[d+3] = v.w;
    }
    const float sqn = sqb[n];

    // ---- fill: round-8 distance arithmetic; dist copy spilled to LDS ----
    float srt[KNN];
#pragma unroll
    for (int j = 0; j < KNN; ++j) {
        int m = j * 64 + lane;
        const float* xm = xb + (size_t)m * D;
        float4 v0 = *(const float4*)(xm);
        float4 v1 = *(const float4*)(xm + 4);
        float4 v2 = *(const float4*)(xm + 8);
        float4 v3 = *(const float4*)(xm + 12);
        float dot = 0.f;
        dot += qx[0]  * v0.x; dot += qx[1]  * v0.y;
        dot += qx[2]  * v0.z; dot += qx[3]  * v0.w;
        dot += qx[4]  * v1.x; dot += qx[5]  * v1.y;
        dot += qx[6]  * v1.z; dot += qx[7]  * v1.w;
        dot += qx[8]  * v2.x; dot += qx[9]  * v2.y;
        dot += qx[10] * v2.z; dot += qx[11] * v2.w;
        dot += qx[12] * v3.x; dot += qx[13] * v3.y;
        dot += qx[14] * v3.z; dot += qx[15] * v3.w;
        float d2 = sqn + sqb[m] - 2.0f * dot;
        float dist = fabsf(sqrtf(fmaxf(d2, 0.f)));   // fabs: -0 -> +0
        distL[j * 64 + lane] = dist;             // own-lane slot
        srt[j] = dist;
    }

    // ---- per-lane bitonic sort (ascending) of the value copy ----
#pragma unroll
    for (int kk = 2; kk <= KNN; kk <<= 1) {
#pragma unroll
        for (int jj = kk >> 1; jj > 0; jj >>= 1) {
#pragma unroll
            for (int i = 0; i < KNN; ++i) {
                int l = i ^ jj;
                if (l > i) {
                    float a = srt[i], c2 = srt[l];
                    if ((i & kk) == 0) { srt[i] = fminf(a, c2); srt[l] = fmaxf(a, c2); }
                    else               { srt[i] = fmaxf(a, c2); srt[l] = fminf(a, c2); }
                }
            }
        }
    }

    // ---- 6 butterfly min-32 merge rounds (values only, duplicates ok) ----
#pragma unroll 1
    for (int s = 1; s <= 32; s <<= 1) {
#pragma unroll
        for (int i = 0; i < KNN / 2; ++i) {
            int r = KNN - 1 - i;
            float o_i = __shfl_xor(srt[r], s, 64);   // partner[31-i]
            float o_r = __shfl_xor(srt[i], s, 64);   // partner[31-r]
            srt[i] = fminf(srt[i], o_i);
            srt[r] = fminf(srt[r], o_r);
        }
#pragma unroll
        for (int jj = 16; jj >= 1; jj >>= 1) {
#pragma unroll
            for (int i = 0; i < KNN; ++i) {
                if ((i & jj) == 0) {
                    int l = i + jj;
                    float a = srt[i], c2 = srt[l];
                    srt[i] = fminf(a, c2);
                    srt[l] = fmaxf(a, c2);
                }
            }
        }
    }
    const float tau = srt[31];                   // exact 32nd smallest value

    // ---- tie-fixup: compact all dist <= tau in ascending global-index order ----
    const unsigned long long lmask = (1ULL << lane) - 1ULL;
    int base = 0;
#pragma unroll
    for (int j = 0; j < KNN; ++j) {
        float oj = distL[j * 64 + lane];         // own-lane slot (no race)
        bool f = (oj <= tau);
        unsigned long long mk = __ballot(f);
        if (f) {
            int pos = base + (int)__popcll(mk & lmask);
            if (pos < CAP)
                collect[pos] =
                    (((unsigned long long)__float_as_uint(oj)) << 11)
                    | (unsigned)(j * 64 + lane);
        }
        base += (int)__popcll(mk);
    }
    int T = base < CAP ? base : CAP;             // wave-uniform, >= 32
    __syncthreads();

    // ---- rank the T collected items (keys globally unique) ----
#pragma unroll 1
    for (int slot = 0; slot < 2; ++slot) {
        int i = lane + slot * 64;
        if (i < T) {
            unsigned long long mk = collect[i];
            int rank = 0;
#pragma unroll 1
            for (int t2 = 0; t2 < T; ++t2)
                rank += (collect[t2] < mk) ? 1 : 0;
            if (rank < KNN)
                sortedm[rank] = (int)(mk & 2047u);
        }
    }
    __syncthreads();

    // ---- matvec: ranked top-32 ----
    float acc[4] = {0.f, 0.f, 0.f, 0.f};
    const float* Tcb = Tc + b * N;
    const float* Tfb = Tf + b * N;
    const float Tcn = Tcb[n], Tfn = Tfb[n];

#pragma unroll
    for (int k = 0; k < KNN; ++k) {
        int wm = sortedm[k];
        float ak = Tcb[wm] - Tcn;
        float bk = Tfb[wm] - Tfn;
        const float* wc = WcT + k * DM + lane;
        const float* wf = WfT + k * DM + lane;
#pragma unroll
        for (int q = 0; q < 4; ++q)
            acc[q] += wc[q * 64] * ak + wf[q * 64] * bk;
    }

    size_t obase = (size_t)qid * DM + lane;
#pragma unroll
    for (int q = 0; q < 4; ++q)
        out[obase + q * 64] = acc[q] + cbias[lane + q * 64];
}

// ---------------------------------------------------------------------------
extern "C" void kernel_launch(void* const* d_in, const int* in_sizes, int n_in,
                              void* d_out, int out_size, void* d_ws, size_t ws_size,
                              hipStream_t stream)
{
    const float* x        = (const float*)d_in[0];   // (B,N,D)
    const float* features = (const float*)d_in[1];   // (B,D)
    const float* W_crd    = (const float*)d_in[2];   // (DM,K)
    const float* W_ftr    = (const float*)d_in[3];   // (DM,K)
    const float* pe_crd   = (const float*)d_in[4];   // (1,1,D,DM)
    const float* pe_ftr   = (const float*)d_in[5];   // (1,1,D,DM)
    // d_in[6] = k (constant 32), ignored

    float* out = (float*)d_out;                      // B*N*DM floats + 1 (pe_loss)

    float* xcrd  = (float*)d_ws;                     // 262144
    float* sqv   = xcrd + (size_t)B * N * D;         // 16384
    float* Tc    = sqv  + B * N;                     // 16384
    float* Tf    = Tc   + B * N;                     // 16384
    float* cbias = Tf   + B * N;                     // 256
    float* WcT   = cbias + DM;                       // 8192
    float* WfT   = WcT + KNN * DM;                   // 8192

    knn_prep<<<65, 256, 0, stream>>>(x, features, W_crd, W_ftr, pe_crd, pe_ftr,
                                     xcrd, sqv, Tc, Tf, WcT, WfT, cbias,
                                     out + (size_t)out_size - 1);
    knn_main<<<B * N, 64, 0, stream>>>(xcrd, sqv, Tc, Tf,
                                       WcT, WfT, cbias, out);
}